// Round 17
// baseline (241.207 us; speedup 1.0000x reference)
//
#include <hip/hip_runtime.h>
#include <stdint.h>

typedef __attribute__((ext_vector_type(8))) short bf16x8;
typedef __attribute__((ext_vector_type(4))) float f32x4;
typedef __attribute__((ext_vector_type(4))) unsigned int u32x4;

#define MFMA16(a, b, c) __builtin_amdgcn_mfma_f32_16x16x32_bf16(a, b, c, 0, 0, 0)

__device__ __forceinline__ float bf2f(unsigned short u) {
    union { unsigned int i; float f; } x; x.i = ((unsigned int)u) << 16; return x.f;
}
__device__ __forceinline__ unsigned short f2bf(float f) {
    union { float f; unsigned int i; } x; x.f = f;
    unsigned int u = x.i;
    return (unsigned short)((u + 0x7FFFu + ((u >> 16) & 1u)) >> 16);
}

// ---------------- P1: hs f32 -> bf16 ----------------
__global__ __launch_bounds__(256) void k_cvt(const float4* __restrict__ in,
                                             unsigned short* __restrict__ out) {
    int i = blockIdx.x * 256 + threadIdx.x;
    float4 v = in[i];
    ushort4 o;
    o.x = f2bf(v.x); o.y = f2bf(v.y); o.z = f2bf(v.z); o.w = f2bf(v.w);
    *(ushort4*)(out + (size_t)i * 4) = o;
}

// ---------------- P2: W [k][n] f32 -> Wt [n][k] bf16 (3 mats) ----------------
__global__ __launch_bounds__(256) void k_wt(const float* __restrict__ W0,
                                            const float* __restrict__ W1,
                                            const float* __restrict__ W2,
                                            unsigned short* __restrict__ Wt) {
    __shared__ float t[64][65];
    const float* Wm = (blockIdx.z == 0) ? W0 : (blockIdx.z == 1) ? W1 : W2;
    int k0 = blockIdx.x * 64, n0 = blockIdx.y * 64;
    for (int it = 0; it < 16; ++it) {
        int idx = threadIdx.x + it * 256;
        int r = idx >> 6, c = idx & 63;
        t[r][c] = Wm[(k0 + r) * 512 + n0 + c];
    }
    __syncthreads();
    unsigned short* dst = Wt + (size_t)blockIdx.z * 512 * 512;
    for (int it = 0; it < 16; ++it) {
        int idx = threadIdx.x + it * 256;
        int nr = idx >> 6, kc = idx & 63;
        dst[(n0 + nr) * 512 + k0 + kc] = f2bf(t[kc][nr]);
    }
}

// ---------------- P3: RoPE cos/sin interleaved table [256][16][2] ----------------
__global__ __launch_bounds__(256) void k_sc(float* __restrict__ cs2) {
    int s = threadIdx.x;
    for (int f = 0; f < 16; ++f) {
        float inv = powf(10000.0f, -(float)f / 16.0f);
        float a = (float)s * inv;
        cs2[(s * 16 + f) * 2 + 0] = cosf(a);
        cs2[(s * 16 + f) * 2 + 1] = sinf(a);
    }
}

// ---------------- G: QKV GEMM -- 512-thread 256x256 tile (template geometry) ----------------
// 8 waves (2M x 4N, 128x64 per wave, acc=128 AGPR), BK=64, dbuf LDS 128KB,
// R13's counted-vmcnt 2-barrier schedule with identical vmcnt math (8 loads/
// thread/STAGE: waves 0-3 stage A, 4-7 stage B -> symmetric counts).
// 64 MFMA per barrier-pair (2x R13), LDS-read:MFMA = 24:64 (vs 16:32).
// (512,2): 2 waves/EU, 1 block/CU; cap 256 VGPR vs demand ~200 -> no spill.
__global__ __launch_bounds__(512, 2) void k_gemm(
    const unsigned short* __restrict__ A,   // hsb [16384][512] bf16
    const unsigned short* __restrict__ Bw,  // wt  [1536][512] bf16 ([n][k])
    const float* __restrict__ bq, const float* __restrict__ bk, const float* __restrict__ bv,
    const float* __restrict__ cs2,
    unsigned short* __restrict__ Qo, unsigned short* __restrict__ Ko, unsigned short* __restrict__ Vo) {
    __shared__ unsigned short a_l[2][16384];   // 256 rows x 64 k, 32KB/buf
    __shared__ unsigned short b_l[2][16384];
    const int tid = threadIdx.x;
    const int wave = tid >> 6, lane = tid & 63;
    const int l15 = lane & 15, l4 = lane >> 4;
    // XCD-chunked swizzle: 384 blocks = 8 XCDs x 48 (bijective: 384%8==0)
    int bid = blockIdx.x;
    int swz = (bid & 7) * 48 + (bid >> 3);
    const int m0 = (swz / 6) * 256;
    const int n0 = (swz % 6) * 256;
    const int wm = (wave >> 2) * 128, wn = (wave & 3) * 64;
    const bool isV = (n0 >= 1024);

    f32x4 zero4 = {0.f, 0.f, 0.f, 0.f};
    f32x4 acc[8][4];
#pragma unroll
    for (int i = 0; i < 8; ++i)
#pragma unroll
        for (int j = 0; j < 4; ++j) acc[i][j] = zero4;

    // Staging split: waves 0-3 stage the A tile, waves 4-7 the B tile.
    // thread covers rows srow0+32*it (it 0..7), source k-chunk XOR-preswizzled.
    const int t8 = tid & 255;
    const int srow0 = t8 >> 3;                       // 0..31
    const int skc = ((tid & 7) ^ (srow0 & 7)) * 8;   // srow&7 invariant under +32
    const bool stB = (wave >= 4);
    const int w4 = wave & 3;
    const unsigned short* gsrc = stB ? (Bw + (size_t)(n0 + srow0) * 512 + skc)
                                     : (A + (size_t)(m0 + srow0) * 512 + skc);

#define STAGE(buf, kt)                                                                          \
    {                                                                                           \
        const unsigned short* ps = gsrc + (kt) * 64;                                            \
        unsigned short* ld = (stB ? &b_l[(buf)][w4 * 512] : &a_l[(buf)][w4 * 512]);             \
        _Pragma("unroll")                                                                       \
        for (int it = 0; it < 8; ++it) {                                                        \
            __builtin_amdgcn_global_load_lds(                                                   \
                (const __attribute__((address_space(1))) unsigned int*)(ps + it * (32 * 512)),  \
                (__attribute__((address_space(3))) unsigned int*)(ld + it * 2048), 16, 0, 0);   \
        }                                                                                       \
    }

    STAGE(0, 0);
    STAGE(1, 1);                     // 16 loads in flight per thread
    int cur = 0;
    for (int kt = 0; kt < 8; ++kt) {
        // barrier1: wait ONLY tile kt (8 older loads); tile kt+1's 8 stay in flight.
        if (kt < 7) { asm volatile("s_waitcnt vmcnt(8)" ::: "memory"); }
        else        { asm volatile("s_waitcnt vmcnt(0)" ::: "memory"); }
        __builtin_amdgcn_s_barrier();
#pragma unroll
        for (int kc = 0; kc < 2; ++kc) {
            const int g = ((kc * 4 + l4) ^ (l15 & 7)) * 8;   // read-side XOR
            bf16x8 af[8], bfr[4];
#pragma unroll
            for (int i = 0; i < 8; ++i)
                af[i] = *(const bf16x8*)&a_l[cur][(wm + i * 16 + l15) * 64 + g];
#pragma unroll
            for (int j = 0; j < 4; ++j)
                bfr[j] = *(const bf16x8*)&b_l[cur][(wn + j * 16 + l15) * 64 + g];
            if (!isV) {
#pragma unroll
                for (int i = 0; i < 8; ++i)
#pragma unroll
                    for (int j = 0; j < 4; ++j) acc[i][j] = MFMA16(af[i], bfr[j], acc[i][j]);
            } else {
                // swapped operands: D[n_local][m_local] -> transposed V output
#pragma unroll
                for (int i = 0; i < 8; ++i)
#pragma unroll
                    for (int j = 0; j < 4; ++j) acc[i][j] = MFMA16(bfr[j], af[i], acc[i][j]);
            }
        }
        // barrier2: all waves done reading buf[cur]; refill gets a full iteration.
        asm volatile("" ::: "memory");
        __builtin_amdgcn_s_barrier();
        if (kt < 6) STAGE(cur, kt + 2);
        cur ^= 1;
    }
#undef STAGE

    if (!isV) {
        const int mat = n0 >> 9;  // 0=Q, 1=K
        unsigned short* __restrict__ dst = (mat == 0) ? Qo : Ko;
        const float* __restrict__ bias = (mat == 0) ? bq : bk;
#pragma unroll
        for (int j = 0; j < 4; ++j) {
            int col = (n0 & 511) + wn + j * 16 + l15;  // 0..511
            float bb = bias[col];
            int h = col >> 5, dh = col & 31, f = dh >> 1;
            float sgn = (col & 1) ? 1.0f : -1.0f;
#pragma unroll
            for (int i = 0; i < 8; ++i) {
#pragma unroll
                for (int r = 0; r < 4; ++r) {
                    int m = m0 + wm + i * 16 + l4 * 4 + r;
                    int b2 = m >> 8, s = m & 255;
                    float t = acc[i][j][r] + bb;
                    float partner = __shfl_xor(t, 1);
                    float2 cn = *(const float2*)(cs2 + (s * 16 + f) * 2);
                    float o = t * cn.x + sgn * partner * cn.y;
                    dst[(size_t)(b2 * 16 + h) * 8192 + s * 32 + dh] = f2bf(o);
                }
            }
        }
    } else {
        // V: acc[i][j] = D[n_local = wn+j*16+l4*4+r][m_local = wm+i*16+l15]
#pragma unroll
        for (int j = 0; j < 4; ++j) {
#pragma unroll
            for (int r = 0; r < 4; ++r) {
                int n = (n0 & 511) + wn + j * 16 + l4 * 4 + r;  // 0..511
                float bb = bv[n];
                int h = n >> 5, dh = n & 31;
#pragma unroll
                for (int i = 0; i < 8; ++i) {
                    int m = m0 + wm + i * 16 + l15;
                    int b2 = m >> 8, s = m & 255;
                    Vo[(size_t)(b2 * 16 + h) * 8192 + dh * 256 + s] = f2bf(acc[i][j][r] + bb);
                }
            }
        }
    }
}

// ---------------- A: attention, normalize-after-PV (R16 verbatim) ----------------
__global__ __launch_bounds__(256, 4) void k_attn(
    const unsigned short* __restrict__ Qm, const unsigned short* __restrict__ Km,
    const unsigned short* __restrict__ Vm,  // Vm is [b][h][dh][s]
    const float* __restrict__ bias_table, float* __restrict__ out) {
    __shared__ unsigned short k_l[256 * 32];   // linear [s][dh], conflict-free (4-chunk rows)
    __shared__ unsigned short vt_l[32 * 256];  // linear [dh][s], chunk-XOR swizzled content
    __shared__ __align__(16) unsigned short brE[512];  // brE[j] = bf16(bias[510-j])
    __shared__ __align__(16) unsigned short brO[512];  // brO[j] = brE-value[j+1]

    const int tid = threadIdx.x, wave = tid >> 6, lane = tid & 63;
    const int l15 = lane & 15, l4 = lane >> 4;
    // 1024 blocks = 8 XCDs x 128
    int bid = blockIdx.x;
    int swz = (bid & 7) * 128 + (bid >> 3);
    const int h = swz & 15, b = swz >> 4;
    const size_t bh = ((size_t)(b * 16 + h)) * 8192;

    // reversed bias tables: bias[x] = bias_table[x*16+h]; value[j] = bias[510-j]
    for (int x = tid; x < 511; x += 256) {
        unsigned short w = f2bf(bias_table[x * 16 + h]);
        brE[510 - x] = w;
        if (x <= 509) brO[509 - x] = w;
    }

    // K stage: straight 16KB copy via global_load_lds
#pragma unroll
    for (int it = 0; it < 4; ++it) {
        int p = it * 256 + wave * 64 + lane;  // 16B chunk index
        __builtin_amdgcn_global_load_lds(
            (const __attribute__((address_space(1))) unsigned int*)(Km + bh + p * 8),
            (__attribute__((address_space(3))) unsigned int*)(k_l + it * 2048 + wave * 512), 16, 0, 0);
    }
    // V stage: source pre-swizzled (chunk c at lds pos c^(dh&7))
#pragma unroll
    for (int it = 0; it < 4; ++it) {
        int p = it * 256 + wave * 64 + lane;
        int dh = p >> 5, cpos = p & 31;
        int srcc = cpos ^ (dh & 7);
        __builtin_amdgcn_global_load_lds(
            (const __attribute__((address_space(1))) unsigned int*)(Vm + bh + dh * 256 + srcc * 8),
            (__attribute__((address_space(3))) unsigned int*)(vt_l + it * 2048 + wave * 512), 16, 0, 0);
    }
    __syncthreads();
    // k_l / vt_l / brE / brO read-only from here -> no more barriers.

    f32x4 zero4 = {0.f, 0.f, 0.f, 0.f};
    const float SCL2 = 0.17677669529663687f * 1.4426950408889634f;
    const int qrow = 16 * wave + l15;
    const bool hi = (l4 >> 1) != 0;   // a
    const bool odd = (l4 & 1) != 0;   // b

    bf16x8 qcur = *(const bf16x8*)(Qm + bh + (size_t)qrow * 32 + l4 * 8);  // qb=0

    for (int qb = 0; qb < 4; ++qb) {
        const int q0 = qb * 64;
        bf16x8 qnext;
        if (qb < 3)
            qnext = *(const bf16x8*)(Qm + bh + (size_t)(q0 + 64 + qrow) * 32 + l4 * 8);

        f32x4 o0 = zero4, o1 = zero4;    // sum exp*V (unnormalized)
        f32x4 c20 = zero4, c21 = zero4;  // sum bias*V
        float s0 = 0.f, s1 = 0.f, s2 = 0.f, s3 = 0.f;

#pragma unroll
        for (int m = 0; m < 8; ++m) {
            bf16x8 kf0 = *(const bf16x8*)&k_l[((2 * m) * 16 + l15) * 32 + l4 * 8];
            bf16x8 kf1 = *(const bf16x8*)&k_l[((2 * m + 1) * 16 + l15) * 32 + l4 * 8];
            f32x4 sca = MFMA16(kf0, qcur, zero4);
            f32x4 scb = MFMA16(kf1, qcur, zero4);
            float e0, e1, e2, e3, e4, e5, e6, e7;
            {
                float x0 = sca[0] * SCL2, x1 = sca[1] * SCL2, x2 = sca[2] * SCL2, x3 = sca[3] * SCL2;
                float x4 = scb[0] * SCL2, x5 = scb[1] * SCL2, x6 = scb[2] * SCL2, x7 = scb[3] * SCL2;
                asm("v_exp_f32 %0, %1" : "=v"(e0) : "v"(x0));
                asm("v_exp_f32 %0, %1" : "=v"(e1) : "v"(x1));
                asm("v_exp_f32 %0, %1" : "=v"(e2) : "v"(x2));
                asm("v_exp_f32 %0, %1" : "=v"(e3) : "v"(x3));
                asm("v_exp_f32 %0, %1" : "=v"(e4) : "v"(x4));
                asm("v_exp_f32 %0, %1" : "=v"(e5) : "v"(x5));
                asm("v_exp_f32 %0, %1" : "=v"(e6) : "v"(x6));
                asm("v_exp_f32 %0, %1" : "=v"(e7) : "v"(x7));
            }
            s0 += e0 + e4; s1 += e1 + e5; s2 += e2 + e6; s3 += e3 + e7;
            unsigned int E0, E1, O0, O1;
            asm("v_cvt_pk_bf16_f32 %0, %1, %2" : "=v"(E0) : "v"(e0), "v"(e1));
            asm("v_cvt_pk_bf16_f32 %0, %1, %2" : "=v"(E1) : "v"(e2), "v"(e3));
            asm("v_cvt_pk_bf16_f32 %0, %1, %2" : "=v"(O0) : "v"(e4), "v"(e5));
            asm("v_cvt_pk_bf16_f32 %0, %1, %2" : "=v"(O1) : "v"(e6), "v"(e7));
            unsigned int m0_ = hi ? O0 : E0, m1_ = hi ? O1 : E1;
            unsigned int s0_ = hi ? E0 : O0, s1_ = hi ? E1 : O1;
            unsigned int g0 = __shfl_xor(s0_, 32), g1 = __shfl_xor(s1_, 32);
            unsigned int X00 = hi ? g0 : m0_, X01 = hi ? g1 : m1_;
            unsigned int X10 = hi ? m0_ : g0, X11 = hi ? m1_ : g1;
            unsigned int k0 = odd ? X10 : X00, k1 = odd ? X11 : X01;
            unsigned int t0 = odd ? X00 : X10, t1 = odd ? X01 : X11;
            unsigned int r0 = __shfl_xor(t0, 16), r1 = __shfl_xor(t1, 16);
            union { unsigned int u[4]; bf16x8 v; } pu;
            pu.u[0] = odd ? r0 : k0; pu.u[1] = odd ? r1 : k1;
            pu.u[2] = odd ? k0 : r0; pu.u[3] = odd ? k1 : r1;
            union { unsigned int u[4]; bf16x8 v; } bu;
            {
                int c = 255 + 32 * m + 8 * l4 - (q0 + qrow);
                const unsigned short* arr = (c & 1) ? brO : brE;
                int cb = c & ~1;
                bu.u[0] = *(const unsigned int*)&arr[cb];
                bu.u[1] = *(const unsigned int*)&arr[cb + 2];
                bu.u[2] = *(const unsigned int*)&arr[cb + 4];
                bu.u[3] = *(const unsigned int*)&arr[cb + 6];
            }
            int vc = (m * 4 + l4) ^ (l15 & 7);
            bf16x8 v0 = *(const bf16x8*)&vt_l[l15 * 256 + vc * 8];
            bf16x8 v1 = *(const bf16x8*)&vt_l[(16 + l15) * 256 + vc * 8];
            o0 = MFMA16(pu.v, v0, o0);
            o1 = MFMA16(pu.v, v1, o1);
            c20 = MFMA16(bu.v, v0, c20);
            c21 = MFMA16(bu.v, v1, c21);
        }

        float sum = (s0 + s1) + (s2 + s3);
        sum += __shfl_xor(sum, 16);
        sum += __shfl_xor(sum, 32);
        float inv = 1.0f / sum;

#pragma unroll
        for (int r = 0; r < 4; ++r) {
            float ivr = __shfl(inv, 4 * l4 + r);
            int s = q0 + 16 * wave + l4 * 4 + r;
            float* po = out + ((size_t)(b * 256 + s)) * 512 + h * 32;
            __builtin_nontemporal_store(o0[r] * ivr + c20[r], po + l15);
            __builtin_nontemporal_store(o1[r] * ivr + c21[r], po + 16 + l15);
        }
        if (qb < 3) qcur = qnext;
    }
}

// ---------------- launch ----------------
extern "C" void kernel_launch(void* const* d_in, const int* in_sizes, int n_in,
                              void* d_out, int out_size, void* d_ws, size_t ws_size,
                              hipStream_t stream) {
    const float* hs = (const float*)d_in[0];
    const float* Wq = (const float*)d_in[1];
    const float* bq = (const float*)d_in[2];
    const float* Wk = (const float*)d_in[3];
    const float* bk = (const float*)d_in[4];
    const float* Wv = (const float*)d_in[5];
    const float* bv = (const float*)d_in[6];
    const float* bt = (const float*)d_in[7];
    float* out = (float*)d_out;

    char* ws = (char*)d_ws;
    unsigned short* hsb = (unsigned short*)ws;                 // 16,777,216 B (row-major bf16)
    unsigned short* wt = (unsigned short*)(ws + 16777216);     //  1,572,864 B ([n][k] row-major)
    unsigned short* Qo = (unsigned short*)(ws + 18350080);     // 16,777,216 B
    unsigned short* Ko = (unsigned short*)(ws + 35127296);     // 16,777,216 B
    unsigned short* Vo = (unsigned short*)(ws + 51904512);     // 16,777,216 B ([b][h][dh][s])
    float* cs2 = (float*)(ws + 68681728);                      //     32,768 B

    hipLaunchKernelGGL(k_cvt, dim3(8192), dim3(256), 0, stream, (const float4*)hs, hsb);
    hipLaunchKernelGGL(k_wt, dim3(8, 8, 3), dim3(256), 0, stream, Wq, Wk, Wv, wt);
    hipLaunchKernelGGL(k_sc, dim3(1), dim3(256), 0, stream, cs2);
    hipLaunchKernelGGL(k_gemm, dim3(384), dim3(512), 0, stream,
                       hsb, wt, bq, bk, bv, cs2, Qo, Ko, Vo);
    hipLaunchKernelGGL(k_attn, dim3(1024), dim3(256), 0, stream,
                       Qo, Ko, Vo, bt, out);
}

// Round 18
// 89.670 us; speedup vs baseline: 2.6899x; 2.6899x over previous
//
#include <hip/hip_runtime.h>
#include <stdint.h>

typedef __attribute__((ext_vector_type(8))) short bf16x8;
typedef __attribute__((ext_vector_type(4))) float f32x4;
typedef __attribute__((ext_vector_type(4))) unsigned int u32x4;

#define MFMA16(a, b, c) __builtin_amdgcn_mfma_f32_16x16x32_bf16(a, b, c, 0, 0, 0)

__device__ __forceinline__ float bf2f(unsigned short u) {
    union { unsigned int i; float f; } x; x.i = ((unsigned int)u) << 16; return x.f;
}
__device__ __forceinline__ unsigned short f2bf(float f) {
    union { float f; unsigned int i; } x; x.f = f;
    unsigned int u = x.i;
    return (unsigned short)((u + 0x7FFFu + ((u >> 16) & 1u)) >> 16);
}

// ---------------- P1: hs f32 -> bf16 ----------------
__global__ __launch_bounds__(256) void k_cvt(const float4* __restrict__ in,
                                             unsigned short* __restrict__ out) {
    int i = blockIdx.x * 256 + threadIdx.x;
    float4 v = in[i];
    ushort4 o;
    o.x = f2bf(v.x); o.y = f2bf(v.y); o.z = f2bf(v.z); o.w = f2bf(v.w);
    *(ushort4*)(out + (size_t)i * 4) = o;
}

// ---------------- P2: W [k][n] f32 -> Wt [n][k] bf16 (3 mats) ----------------
__global__ __launch_bounds__(256) void k_wt(const float* __restrict__ W0,
                                            const float* __restrict__ W1,
                                            const float* __restrict__ W2,
                                            unsigned short* __restrict__ Wt) {
    __shared__ float t[64][65];
    const float* Wm = (blockIdx.z == 0) ? W0 : (blockIdx.z == 1) ? W1 : W2;
    int k0 = blockIdx.x * 64, n0 = blockIdx.y * 64;
    for (int it = 0; it < 16; ++it) {
        int idx = threadIdx.x + it * 256;
        int r = idx >> 6, c = idx & 63;
        t[r][c] = Wm[(k0 + r) * 512 + n0 + c];
    }
    __syncthreads();
    unsigned short* dst = Wt + (size_t)blockIdx.z * 512 * 512;
    for (int it = 0; it < 16; ++it) {
        int idx = threadIdx.x + it * 256;
        int nr = idx >> 6, kc = idx & 63;
        dst[(n0 + nr) * 512 + k0 + kc] = f2bf(t[kc][nr]);
    }
}

// ---------------- P3: RoPE cos/sin interleaved table [256][16][2] ----------------
__global__ __launch_bounds__(256) void k_sc(float* __restrict__ cs2) {
    int s = threadIdx.x;
    for (int f = 0; f < 16; ++f) {
        float inv = powf(10000.0f, -(float)f / 16.0f);
        float a = (float)s * inv;
        cs2[(s * 16 + f) * 2 + 0] = cosf(a);
        cs2[(s * 16 + f) * 2 + 1] = sinf(a);
    }
}

// ---------------- G: QKV GEMM (R13 verbatim -- measured best 44.4 us) ----------------
// 128x128 tile, BK=64, dbuf LDS A+B, (256,2), counted vmcnt(8) + 2 barriers/step.
// Structure ledger (10 variants): anything that raises reg demand past the
// (256,2) footprint spills (R4/R5/R10/R17); LDS>64KB drops to 1 block/CU (R14);
// BK=32 inflates barriers+fetch (R12). This point is the constrained optimum.
__global__ __launch_bounds__(256, 2) void k_gemm(
    const unsigned short* __restrict__ A,   // hsb [16384][512] bf16
    const unsigned short* __restrict__ Bw,  // wt  [1536][512] bf16 ([n][k])
    const float* __restrict__ bq, const float* __restrict__ bk, const float* __restrict__ bv,
    const float* __restrict__ cs2,
    unsigned short* __restrict__ Qo, unsigned short* __restrict__ Ko, unsigned short* __restrict__ Vo) {
    __shared__ unsigned short a_l[2][8192];
    __shared__ unsigned short b_l[2][8192];
    const int tid = threadIdx.x;
    const int wave = tid >> 6, lane = tid & 63;
    const int l15 = lane & 15, l4 = lane >> 4;
    // XCD-chunked swizzle: 1536 blocks = 8 XCDs x 192 (16 m-tiles each, n fast)
    int bid = blockIdx.x;
    int swz = (bid & 7) * 192 + (bid >> 3);
    const int m0 = (swz / 12) * 128;
    const int n0 = (swz % 12) * 128;
    const int wm = (wave >> 1) * 64, wn = (wave & 1) * 64;
    const bool isV = (n0 >= 1024);

    f32x4 zero4 = {0.f, 0.f, 0.f, 0.f};
    f32x4 acc[4][4];
#pragma unroll
    for (int i = 0; i < 4; ++i)
#pragma unroll
        for (int j = 0; j < 4; ++j) acc[i][j] = zero4;

    // staging: thread t covers row (t>>3)+32*it, source k-chunk XOR-preswizzled
    const int srow = tid >> 3;
    const int skc = ((tid & 7) ^ (srow & 7)) * 8;
    const unsigned short* ga = A + (size_t)(m0 + srow) * 512 + skc;
    const unsigned short* gb = Bw + (size_t)(n0 + srow) * 512 + skc;

#define STAGE(buf, kt)                                                                          \
    {                                                                                           \
        const unsigned short* pa = ga + (kt) * 64;                                              \
        const unsigned short* pb = gb + (kt) * 64;                                              \
        unsigned short* la = &a_l[(buf)][wave * 512];                                           \
        unsigned short* lb = &b_l[(buf)][wave * 512];                                           \
        _Pragma("unroll")                                                                       \
        for (int it = 0; it < 4; ++it) {                                                        \
            __builtin_amdgcn_global_load_lds(                                                   \
                (const __attribute__((address_space(1))) unsigned int*)(pa + it * (32 * 512)),  \
                (__attribute__((address_space(3))) unsigned int*)(la + it * 2048), 16, 0, 0);   \
            __builtin_amdgcn_global_load_lds(                                                   \
                (const __attribute__((address_space(1))) unsigned int*)(pb + it * (32 * 512)),  \
                (__attribute__((address_space(3))) unsigned int*)(lb + it * 2048), 16, 0, 0);   \
        }                                                                                       \
    }

    STAGE(0, 0);
    STAGE(1, 1);                     // 16 loads in flight
    int cur = 0;
    for (int kt = 0; kt < 8; ++kt) {
        // barrier1: wait ONLY tile kt (8 older loads); tile kt+1's 8 stay in flight.
        if (kt < 7) { asm volatile("s_waitcnt vmcnt(8)" ::: "memory"); }
        else        { asm volatile("s_waitcnt vmcnt(0)" ::: "memory"); }
        __builtin_amdgcn_s_barrier();
#pragma unroll
        for (int kc = 0; kc < 2; ++kc) {
            bf16x8 af[4], bfr[4];
#pragma unroll
            for (int i = 0; i < 4; ++i) {
                int g = ((kc * 4 + l4) ^ (l15 & 7)) * 8;   // read-side XOR
                af[i] = *(const bf16x8*)&a_l[cur][(wm + i * 16 + l15) * 64 + g];
            }
#pragma unroll
            for (int j = 0; j < 4; ++j) {
                int g = ((kc * 4 + l4) ^ (l15 & 7)) * 8;
                bfr[j] = *(const bf16x8*)&b_l[cur][(wn + j * 16 + l15) * 64 + g];
            }
            if (!isV) {
#pragma unroll
                for (int i = 0; i < 4; ++i)
#pragma unroll
                    for (int j = 0; j < 4; ++j) acc[i][j] = MFMA16(af[i], bfr[j], acc[i][j]);
            } else {
                // swapped operands: D[n_local][m_local] -> transposed V output
#pragma unroll
                for (int i = 0; i < 4; ++i)
#pragma unroll
                    for (int j = 0; j < 4; ++j) acc[i][j] = MFMA16(bfr[j], af[i], acc[i][j]);
            }
        }
        // barrier2: all waves done reading buf[cur]; refill gets a full iteration.
        asm volatile("" ::: "memory");
        __builtin_amdgcn_s_barrier();
        if (kt < 6) STAGE(cur, kt + 2);
        cur ^= 1;
    }
#undef STAGE

    if (!isV) {
        const int mat = n0 >> 9;  // 0=Q, 1=K
        unsigned short* __restrict__ dst = (mat == 0) ? Qo : Ko;
        const float* __restrict__ bias = (mat == 0) ? bq : bk;
#pragma unroll
        for (int j = 0; j < 4; ++j) {
            int col = (n0 & 511) + wn + j * 16 + l15;  // 0..511
            float bb = bias[col];
            int h = col >> 5, dh = col & 31, f = dh >> 1;
            float sgn = (col & 1) ? 1.0f : -1.0f;
#pragma unroll
            for (int i = 0; i < 4; ++i) {
#pragma unroll
                for (int r = 0; r < 4; ++r) {
                    int m = m0 + wm + i * 16 + l4 * 4 + r;
                    int b2 = m >> 8, s = m & 255;
                    float t = acc[i][j][r] + bb;
                    float partner = __shfl_xor(t, 1);
                    float2 cn = *(const float2*)(cs2 + (s * 16 + f) * 2);
                    float o = t * cn.x + sgn * partner * cn.y;
                    dst[(size_t)(b2 * 16 + h) * 8192 + s * 32 + dh] = f2bf(o);
                }
            }
        }
    } else {
        // V: acc[i][j] = D[n_local = wn+j*16+l4*4+r][m_local = wm+i*16+l15]
#pragma unroll
        for (int j = 0; j < 4; ++j) {
#pragma unroll
            for (int r = 0; r < 4; ++r) {
                int n = (n0 & 511) + wn + j * 16 + l4 * 4 + r;  // 0..511
                float bb = bv[n];
                int h = n >> 5, dh = n & 31;
#pragma unroll
                for (int i = 0; i < 4; ++i) {
                    int m = m0 + wm + i * 16 + l15;
                    int b2 = m >> 8, s = m & 255;
                    Vo[(size_t)(b2 * 16 + h) * 8192 + dh * 256 + s] = f2bf(acc[i][j][r] + bb);
                }
            }
        }
    }
}

// ---------------- A: attention, normalize-after-PV (R16 verbatim) ----------------
__global__ __launch_bounds__(256, 4) void k_attn(
    const unsigned short* __restrict__ Qm, const unsigned short* __restrict__ Km,
    const unsigned short* __restrict__ Vm,  // Vm is [b][h][dh][s]
    const float* __restrict__ bias_table, float* __restrict__ out) {
    __shared__ unsigned short k_l[256 * 32];   // linear [s][dh], conflict-free (4-chunk rows)
    __shared__ unsigned short vt_l[32 * 256];  // linear [dh][s], chunk-XOR swizzled content
    __shared__ __align__(16) unsigned short brE[512];  // brE[j] = bf16(bias[510-j])
    __shared__ __align__(16) unsigned short brO[512];  // brO[j] = brE-value[j+1]

    const int tid = threadIdx.x, wave = tid >> 6, lane = tid & 63;
    const int l15 = lane & 15, l4 = lane >> 4;
    // 1024 blocks = 8 XCDs x 128
    int bid = blockIdx.x;
    int swz = (bid & 7) * 128 + (bid >> 3);
    const int h = swz & 15, b = swz >> 4;
    const size_t bh = ((size_t)(b * 16 + h)) * 8192;

    // reversed bias tables: bias[x] = bias_table[x*16+h]; value[j] = bias[510-j]
    for (int x = tid; x < 511; x += 256) {
        unsigned short w = f2bf(bias_table[x * 16 + h]);
        brE[510 - x] = w;
        if (x <= 509) brO[509 - x] = w;
    }

    // K stage: straight 16KB copy via global_load_lds
#pragma unroll
    for (int it = 0; it < 4; ++it) {
        int p = it * 256 + wave * 64 + lane;  // 16B chunk index
        __builtin_amdgcn_global_load_lds(
            (const __attribute__((address_space(1))) unsigned int*)(Km + bh + p * 8),
            (__attribute__((address_space(3))) unsigned int*)(k_l + it * 2048 + wave * 512), 16, 0, 0);
    }
    // V stage: source pre-swizzled (chunk c at lds pos c^(dh&7))
#pragma unroll
    for (int it = 0; it < 4; ++it) {
        int p = it * 256 + wave * 64 + lane;
        int dh = p >> 5, cpos = p & 31;
        int srcc = cpos ^ (dh & 7);
        __builtin_amdgcn_global_load_lds(
            (const __attribute__((address_space(1))) unsigned int*)(Vm + bh + dh * 256 + srcc * 8),
            (__attribute__((address_space(3))) unsigned int*)(vt_l + it * 2048 + wave * 512), 16, 0, 0);
    }
    __syncthreads();
    // k_l / vt_l / brE / brO read-only from here -> no more barriers.

    f32x4 zero4 = {0.f, 0.f, 0.f, 0.f};
    const float SCL2 = 0.17677669529663687f * 1.4426950408889634f;
    const int qrow = 16 * wave + l15;
    const bool hi = (l4 >> 1) != 0;   // a
    const bool odd = (l4 & 1) != 0;   // b

    bf16x8 qcur = *(const bf16x8*)(Qm + bh + (size_t)qrow * 32 + l4 * 8);  // qb=0

    for (int qb = 0; qb < 4; ++qb) {
        const int q0 = qb * 64;
        bf16x8 qnext;
        if (qb < 3)
            qnext = *(const bf16x8*)(Qm + bh + (size_t)(q0 + 64 + qrow) * 32 + l4 * 8);

        f32x4 o0 = zero4, o1 = zero4;    // sum exp*V (unnormalized)
        f32x4 c20 = zero4, c21 = zero4;  // sum bias*V
        float s0 = 0.f, s1 = 0.f, s2 = 0.f, s3 = 0.f;

#pragma unroll
        for (int m = 0; m < 8; ++m) {
            bf16x8 kf0 = *(const bf16x8*)&k_l[((2 * m) * 16 + l15) * 32 + l4 * 8];
            bf16x8 kf1 = *(const bf16x8*)&k_l[((2 * m + 1) * 16 + l15) * 32 + l4 * 8];
            f32x4 sca = MFMA16(kf0, qcur, zero4);
            f32x4 scb = MFMA16(kf1, qcur, zero4);
            float e0, e1, e2, e3, e4, e5, e6, e7;
            {
                float x0 = sca[0] * SCL2, x1 = sca[1] * SCL2, x2 = sca[2] * SCL2, x3 = sca[3] * SCL2;
                float x4 = scb[0] * SCL2, x5 = scb[1] * SCL2, x6 = scb[2] * SCL2, x7 = scb[3] * SCL2;
                asm("v_exp_f32 %0, %1" : "=v"(e0) : "v"(x0));
                asm("v_exp_f32 %0, %1" : "=v"(e1) : "v"(x1));
                asm("v_exp_f32 %0, %1" : "=v"(e2) : "v"(x2));
                asm("v_exp_f32 %0, %1" : "=v"(e3) : "v"(x3));
                asm("v_exp_f32 %0, %1" : "=v"(e4) : "v"(x4));
                asm("v_exp_f32 %0, %1" : "=v"(e5) : "v"(x5));
                asm("v_exp_f32 %0, %1" : "=v"(e6) : "v"(x6));
                asm("v_exp_f32 %0, %1" : "=v"(e7) : "v"(x7));
            }
            s0 += e0 + e4; s1 += e1 + e5; s2 += e2 + e6; s3 += e3 + e7;
            unsigned int E0, E1, O0, O1;
            asm("v_cvt_pk_bf16_f32 %0, %1, %2" : "=v"(E0) : "v"(e0), "v"(e1));
            asm("v_cvt_pk_bf16_f32 %0, %1, %2" : "=v"(E1) : "v"(e2), "v"(e3));
            asm("v_cvt_pk_bf16_f32 %0, %1, %2" : "=v"(O0) : "v"(e4), "v"(e5));
            asm("v_cvt_pk_bf16_f32 %0, %1, %2" : "=v"(O1) : "v"(e6), "v"(e7));
            unsigned int m0_ = hi ? O0 : E0, m1_ = hi ? O1 : E1;
            unsigned int s0_ = hi ? E0 : O0, s1_ = hi ? E1 : O1;
            unsigned int g0 = __shfl_xor(s0_, 32), g1 = __shfl_xor(s1_, 32);
            unsigned int X00 = hi ? g0 : m0_, X01 = hi ? g1 : m1_;
            unsigned int X10 = hi ? m0_ : g0, X11 = hi ? m1_ : g1;
            unsigned int k0 = odd ? X10 : X00, k1 = odd ? X11 : X01;
            unsigned int t0 = odd ? X00 : X10, t1 = odd ? X01 : X11;
            unsigned int r0 = __shfl_xor(t0, 16), r1 = __shfl_xor(t1, 16);
            union { unsigned int u[4]; bf16x8 v; } pu;
            pu.u[0] = odd ? r0 : k0; pu.u[1] = odd ? r1 : k1;
            pu.u[2] = odd ? k0 : r0; pu.u[3] = odd ? k1 : r1;
            union { unsigned int u[4]; bf16x8 v; } bu;
            {
                int c = 255 + 32 * m + 8 * l4 - (q0 + qrow);
                const unsigned short* arr = (c & 1) ? brO : brE;
                int cb = c & ~1;
                bu.u[0] = *(const unsigned int*)&arr[cb];
                bu.u[1] = *(const unsigned int*)&arr[cb + 2];
                bu.u[2] = *(const unsigned int*)&arr[cb + 4];
                bu.u[3] = *(const unsigned int*)&arr[cb + 6];
            }
            int vc = (m * 4 + l4) ^ (l15 & 7);
            bf16x8 v0 = *(const bf16x8*)&vt_l[l15 * 256 + vc * 8];
            bf16x8 v1 = *(const bf16x8*)&vt_l[(16 + l15) * 256 + vc * 8];
            o0 = MFMA16(pu.v, v0, o0);
            o1 = MFMA16(pu.v, v1, o1);
            c20 = MFMA16(bu.v, v0, c20);
            c21 = MFMA16(bu.v, v1, c21);
        }

        float sum = (s0 + s1) + (s2 + s3);
        sum += __shfl_xor(sum, 16);
        sum += __shfl_xor(sum, 32);
        float inv = 1.0f / sum;

#pragma unroll
        for (int r = 0; r < 4; ++r) {
            float ivr = __shfl(inv, 4 * l4 + r);
            int s = q0 + 16 * wave + l4 * 4 + r;
            float* po = out + ((size_t)(b * 256 + s)) * 512 + h * 32;
            __builtin_nontemporal_store(o0[r] * ivr + c20[r], po + l15);
            __builtin_nontemporal_store(o1[r] * ivr + c21[r], po + 16 + l15);
        }
        if (qb < 3) qcur = qnext;
    }
}

// ---------------- launch ----------------
extern "C" void kernel_launch(void* const* d_in, const int* in_sizes, int n_in,
                              void* d_out, int out_size, void* d_ws, size_t ws_size,
                              hipStream_t stream) {
    const float* hs = (const float*)d_in[0];
    const float* Wq = (const float*)d_in[1];
    const float* bq = (const float*)d_in[2];
    const float* Wk = (const float*)d_in[3];
    const float* bk = (const float*)d_in[4];
    const float* Wv = (const float*)d_in[5];
    const float* bv = (const float*)d_in[6];
    const float* bt = (const float*)d_in[7];
    float* out = (float*)d_out;

    char* ws = (char*)d_ws;
    unsigned short* hsb = (unsigned short*)ws;                 // 16,777,216 B (row-major bf16)
    unsigned short* wt = (unsigned short*)(ws + 16777216);     //  1,572,864 B ([n][k] row-major)
    unsigned short* Qo = (unsigned short*)(ws + 18350080);     // 16,777,216 B
    unsigned short* Ko = (unsigned short*)(ws + 35127296);     // 16,777,216 B
    unsigned short* Vo = (unsigned short*)(ws + 51904512);     // 16,777,216 B ([b][h][dh][s])
    float* cs2 = (float*)(ws + 68681728);                      //     32,768 B

    hipLaunchKernelGGL(k_cvt, dim3(8192), dim3(256), 0, stream, (const float4*)hs, hsb);
    hipLaunchKernelGGL(k_wt, dim3(8, 8, 3), dim3(256), 0, stream, Wq, Wk, Wv, wt);
    hipLaunchKernelGGL(k_sc, dim3(1), dim3(256), 0, stream, cs2);
    hipLaunchKernelGGL(k_gemm, dim3(1536), dim3(256), 0, stream,
                       hsb, wt, bq, bk, bv, cs2, Qo, Ko, Vo);
    hipLaunchKernelGGL(k_attn, dim3(1024), dim3(256), 0, stream,
                       Qo, Ko, Vo, bt, out);
}

// Round 19
// 89.340 us; speedup vs baseline: 2.6999x; 1.0037x over previous
//
#include <hip/hip_runtime.h>
#include <stdint.h>

typedef __attribute__((ext_vector_type(8))) short bf16x8;
typedef __attribute__((ext_vector_type(4))) float f32x4;
typedef __attribute__((ext_vector_type(4))) unsigned int u32x4;

#define MFMA16(a, b, c) __builtin_amdgcn_mfma_f32_16x16x32_bf16(a, b, c, 0, 0, 0)

__device__ __forceinline__ float bf2f(unsigned short u) {
    union { unsigned int i; float f; } x; x.i = ((unsigned int)u) << 16; return x.f;
}
__device__ __forceinline__ unsigned short f2bf(float f) {
    union { float f; unsigned int i; } x; x.f = f;
    unsigned int u = x.i;
    return (unsigned short)((u + 0x7FFFu + ((u >> 16) & 1u)) >> 16);
}

// ---------------- P1: hs f32 -> bf16 ----------------
__global__ __launch_bounds__(256) void k_cvt(const float4* __restrict__ in,
                                             unsigned short* __restrict__ out) {
    int i = blockIdx.x * 256 + threadIdx.x;
    float4 v = in[i];
    ushort4 o;
    o.x = f2bf(v.x); o.y = f2bf(v.y); o.z = f2bf(v.z); o.w = f2bf(v.w);
    *(ushort4*)(out + (size_t)i * 4) = o;
}

// ---------------- P2: W [k][n] f32 -> Wt [n][k] bf16 (3 mats) ----------------
__global__ __launch_bounds__(256) void k_wt(const float* __restrict__ W0,
                                            const float* __restrict__ W1,
                                            const float* __restrict__ W2,
                                            unsigned short* __restrict__ Wt) {
    __shared__ float t[64][65];
    const float* Wm = (blockIdx.z == 0) ? W0 : (blockIdx.z == 1) ? W1 : W2;
    int k0 = blockIdx.x * 64, n0 = blockIdx.y * 64;
    for (int it = 0; it < 16; ++it) {
        int idx = threadIdx.x + it * 256;
        int r = idx >> 6, c = idx & 63;
        t[r][c] = Wm[(k0 + r) * 512 + n0 + c];
    }
    __syncthreads();
    unsigned short* dst = Wt + (size_t)blockIdx.z * 512 * 512;
    for (int it = 0; it < 16; ++it) {
        int idx = threadIdx.x + it * 256;
        int nr = idx >> 6, kc = idx & 63;
        dst[(n0 + nr) * 512 + k0 + kc] = f2bf(t[kc][nr]);
    }
}

// ---------------- P3: RoPE cos/sin interleaved table [256][16][2] ----------------
__global__ __launch_bounds__(256) void k_sc(float* __restrict__ cs2) {
    int s = threadIdx.x;
    for (int f = 0; f < 16; ++f) {
        float inv = powf(10000.0f, -(float)f / 16.0f);
        float a = (float)s * inv;
        cs2[(s * 16 + f) * 2 + 0] = cosf(a);
        cs2[(s * 16 + f) * 2 + 1] = sinf(a);
    }
}

// ---------------- G: QKV GEMM (R13 verbatim -- measured best 44.4 us) ----------------
__global__ __launch_bounds__(256, 2) void k_gemm(
    const unsigned short* __restrict__ A,   // hsb [16384][512] bf16
    const unsigned short* __restrict__ Bw,  // wt  [1536][512] bf16 ([n][k])
    const float* __restrict__ bq, const float* __restrict__ bk, const float* __restrict__ bv,
    const float* __restrict__ cs2,
    unsigned short* __restrict__ Qo, unsigned short* __restrict__ Ko, unsigned short* __restrict__ Vo) {
    __shared__ unsigned short a_l[2][8192];
    __shared__ unsigned short b_l[2][8192];
    const int tid = threadIdx.x;
    const int wave = tid >> 6, lane = tid & 63;
    const int l15 = lane & 15, l4 = lane >> 4;
    // XCD-chunked swizzle: 1536 blocks = 8 XCDs x 192 (16 m-tiles each, n fast)
    int bid = blockIdx.x;
    int swz = (bid & 7) * 192 + (bid >> 3);
    const int m0 = (swz / 12) * 128;
    const int n0 = (swz % 12) * 128;
    const int wm = (wave >> 1) * 64, wn = (wave & 1) * 64;
    const bool isV = (n0 >= 1024);

    f32x4 zero4 = {0.f, 0.f, 0.f, 0.f};
    f32x4 acc[4][4];
#pragma unroll
    for (int i = 0; i < 4; ++i)
#pragma unroll
        for (int j = 0; j < 4; ++j) acc[i][j] = zero4;

    // staging: thread t covers row (t>>3)+32*it, source k-chunk XOR-preswizzled
    const int srow = tid >> 3;
    const int skc = ((tid & 7) ^ (srow & 7)) * 8;
    const unsigned short* ga = A + (size_t)(m0 + srow) * 512 + skc;
    const unsigned short* gb = Bw + (size_t)(n0 + srow) * 512 + skc;

#define STAGE(buf, kt)                                                                          \
    {                                                                                           \
        const unsigned short* pa = ga + (kt) * 64;                                              \
        const unsigned short* pb = gb + (kt) * 64;                                              \
        unsigned short* la = &a_l[(buf)][wave * 512];                                           \
        unsigned short* lb = &b_l[(buf)][wave * 512];                                           \
        _Pragma("unroll")                                                                       \
        for (int it = 0; it < 4; ++it) {                                                        \
            __builtin_amdgcn_global_load_lds(                                                   \
                (const __attribute__((address_space(1))) unsigned int*)(pa + it * (32 * 512)),  \
                (__attribute__((address_space(3))) unsigned int*)(la + it * 2048), 16, 0, 0);   \
            __builtin_amdgcn_global_load_lds(                                                   \
                (const __attribute__((address_space(1))) unsigned int*)(pb + it * (32 * 512)),  \
                (__attribute__((address_space(3))) unsigned int*)(lb + it * 2048), 16, 0, 0);   \
        }                                                                                       \
    }

    STAGE(0, 0);
    STAGE(1, 1);                     // 16 loads in flight
    int cur = 0;
    for (int kt = 0; kt < 8; ++kt) {
        // barrier1: wait ONLY tile kt (8 older loads); tile kt+1's 8 stay in flight.
        if (kt < 7) { asm volatile("s_waitcnt vmcnt(8)" ::: "memory"); }
        else        { asm volatile("s_waitcnt vmcnt(0)" ::: "memory"); }
        __builtin_amdgcn_s_barrier();
#pragma unroll
        for (int kc = 0; kc < 2; ++kc) {
            bf16x8 af[4], bfr[4];
#pragma unroll
            for (int i = 0; i < 4; ++i) {
                int g = ((kc * 4 + l4) ^ (l15 & 7)) * 8;   // read-side XOR
                af[i] = *(const bf16x8*)&a_l[cur][(wm + i * 16 + l15) * 64 + g];
            }
#pragma unroll
            for (int j = 0; j < 4; ++j) {
                int g = ((kc * 4 + l4) ^ (l15 & 7)) * 8;
                bfr[j] = *(const bf16x8*)&b_l[cur][(wn + j * 16 + l15) * 64 + g];
            }
            if (!isV) {
#pragma unroll
                for (int i = 0; i < 4; ++i)
#pragma unroll
                    for (int j = 0; j < 4; ++j) acc[i][j] = MFMA16(af[i], bfr[j], acc[i][j]);
            } else {
                // swapped operands: D[n_local][m_local] -> transposed V output
#pragma unroll
                for (int i = 0; i < 4; ++i)
#pragma unroll
                    for (int j = 0; j < 4; ++j) acc[i][j] = MFMA16(bfr[j], af[i], acc[i][j]);
            }
        }
        // barrier2: all waves done reading buf[cur]; refill gets a full iteration.
        asm volatile("" ::: "memory");
        __builtin_amdgcn_s_barrier();
        if (kt < 6) STAGE(cur, kt + 2);
        cur ^= 1;
    }
#undef STAGE

    if (!isV) {
        const int mat = n0 >> 9;  // 0=Q, 1=K
        unsigned short* __restrict__ dst = (mat == 0) ? Qo : Ko;
        const float* __restrict__ bias = (mat == 0) ? bq : bk;
#pragma unroll
        for (int j = 0; j < 4; ++j) {
            int col = (n0 & 511) + wn + j * 16 + l15;  // 0..511
            float bb = bias[col];
            int h = col >> 5, dh = col & 31, f = dh >> 1;
            float sgn = (col & 1) ? 1.0f : -1.0f;
#pragma unroll
            for (int i = 0; i < 4; ++i) {
#pragma unroll
                for (int r = 0; r < 4; ++r) {
                    int m = m0 + wm + i * 16 + l4 * 4 + r;
                    int b2 = m >> 8, s = m & 255;
                    float t = acc[i][j][r] + bb;
                    float partner = __shfl_xor(t, 1);
                    float2 cn = *(const float2*)(cs2 + (s * 16 + f) * 2);
                    float o = t * cn.x + sgn * partner * cn.y;
                    dst[(size_t)(b2 * 16 + h) * 8192 + s * 32 + dh] = f2bf(o);
                }
            }
        }
    } else {
        // V: acc[i][j] = D[n_local = wn+j*16+l4*4+r][m_local = wm+i*16+l15]
#pragma unroll
        for (int j = 0; j < 4; ++j) {
#pragma unroll
            for (int r = 0; r < 4; ++r) {
                int n = (n0 & 511) + wn + j * 16 + l4 * 4 + r;  // 0..511
                float bb = bv[n];
                int h = n >> 5, dh = n & 31;
#pragma unroll
                for (int i = 0; i < 4; ++i) {
                    int m = m0 + wm + i * 16 + l15;
                    int b2 = m >> 8, s = m & 255;
                    Vo[(size_t)(b2 * 16 + h) * 8192 + dh * 256 + s] = f2bf(acc[i][j][r] + bb);
                }
            }
        }
    }
}

// ---------------- A: attention, normalize-after-PV + K-tile XOR swizzle ----------------
// NEW vs R16: k_l both-sides swizzle (rule 21). Linear [s][32] rows (64B) put
// QK^T's 16 l15-rows in 2 of 8 16B-slots per 128B window -> 8-way conflict on
// 64 ds_read_b128/wave. Store chunk pos p holds source chunk (p&3)^((row>>1)&3);
// read chunk l4 at pos l4^((l15>>1)&3) (ct*16 = 0 mod 8 on row>>1&3) -> 8
// consecutive rows cover all 8 slots -> 2-way (free).
__global__ __launch_bounds__(256, 4) void k_attn(
    const unsigned short* __restrict__ Qm, const unsigned short* __restrict__ Km,
    const unsigned short* __restrict__ Vm,  // Vm is [b][h][dh][s]
    const float* __restrict__ bias_table, float* __restrict__ out) {
    __shared__ unsigned short k_l[256 * 32];   // [s][dh], chunk-XOR swizzled content
    __shared__ unsigned short vt_l[32 * 256];  // linear [dh][s], chunk-XOR swizzled content
    __shared__ __align__(16) unsigned short brE[512];  // brE[j] = bf16(bias[510-j])
    __shared__ __align__(16) unsigned short brO[512];  // brO[j] = brE-value[j+1]

    const int tid = threadIdx.x, wave = tid >> 6, lane = tid & 63;
    const int l15 = lane & 15, l4 = lane >> 4;
    // 1024 blocks = 8 XCDs x 128
    int bid = blockIdx.x;
    int swz = (bid & 7) * 128 + (bid >> 3);
    const int h = swz & 15, b = swz >> 4;
    const size_t bh = ((size_t)(b * 16 + h)) * 8192;

    // reversed bias tables: bias[x] = bias_table[x*16+h]; value[j] = bias[510-j]
    for (int x = tid; x < 511; x += 256) {
        unsigned short w = f2bf(bias_table[x * 16 + h]);
        brE[510 - x] = w;
        if (x <= 509) brO[509 - x] = w;
    }

    // K stage: source pre-swizzled (pos p holds row chunk (p&3)^((row>>1)&3))
#pragma unroll
    for (int it = 0; it < 4; ++it) {
        int p = it * 256 + wave * 64 + lane;  // 16B chunk index 0..1023
        int row = p >> 2, cpos = p & 3;
        int srcc = cpos ^ ((row >> 1) & 3);
        __builtin_amdgcn_global_load_lds(
            (const __attribute__((address_space(1))) unsigned int*)(Km + bh + (size_t)row * 32 + srcc * 8),
            (__attribute__((address_space(3))) unsigned int*)(k_l + it * 2048 + wave * 512), 16, 0, 0);
    }
    // V stage: source pre-swizzled (chunk c at lds pos c^(dh&7))
#pragma unroll
    for (int it = 0; it < 4; ++it) {
        int p = it * 256 + wave * 64 + lane;
        int dh = p >> 5, cpos = p & 31;
        int srcc = cpos ^ (dh & 7);
        __builtin_amdgcn_global_load_lds(
            (const __attribute__((address_space(1))) unsigned int*)(Vm + bh + dh * 256 + srcc * 8),
            (__attribute__((address_space(3))) unsigned int*)(vt_l + it * 2048 + wave * 512), 16, 0, 0);
    }
    __syncthreads();
    // k_l / vt_l / brE / brO read-only from here -> no more barriers.

    f32x4 zero4 = {0.f, 0.f, 0.f, 0.f};
    const float SCL2 = 0.17677669529663687f * 1.4426950408889634f;
    const int qrow = 16 * wave + l15;
    const bool hi = (l4 >> 1) != 0;   // a
    const bool odd = (l4 & 1) != 0;   // b
    const int kg = (l4 ^ ((l15 >> 1) & 3)) * 8;   // swizzled K-chunk read offset

    bf16x8 qcur = *(const bf16x8*)(Qm + bh + (size_t)qrow * 32 + l4 * 8);  // qb=0

    for (int qb = 0; qb < 4; ++qb) {
        const int q0 = qb * 64;
        bf16x8 qnext;
        if (qb < 3)
            qnext = *(const bf16x8*)(Qm + bh + (size_t)(q0 + 64 + qrow) * 32 + l4 * 8);

        f32x4 o0 = zero4, o1 = zero4;    // sum exp*V (unnormalized)
        f32x4 c20 = zero4, c21 = zero4;  // sum bias*V
        float s0 = 0.f, s1 = 0.f, s2 = 0.f, s3 = 0.f;

#pragma unroll
        for (int m = 0; m < 8; ++m) {
            bf16x8 kf0 = *(const bf16x8*)&k_l[((2 * m) * 16 + l15) * 32 + kg];
            bf16x8 kf1 = *(const bf16x8*)&k_l[((2 * m + 1) * 16 + l15) * 32 + kg];
            f32x4 sca = MFMA16(kf0, qcur, zero4);
            f32x4 scb = MFMA16(kf1, qcur, zero4);
            float e0, e1, e2, e3, e4, e5, e6, e7;
            {
                float x0 = sca[0] * SCL2, x1 = sca[1] * SCL2, x2 = sca[2] * SCL2, x3 = sca[3] * SCL2;
                float x4 = scb[0] * SCL2, x5 = scb[1] * SCL2, x6 = scb[2] * SCL2, x7 = scb[3] * SCL2;
                asm("v_exp_f32 %0, %1" : "=v"(e0) : "v"(x0));
                asm("v_exp_f32 %0, %1" : "=v"(e1) : "v"(x1));
                asm("v_exp_f32 %0, %1" : "=v"(e2) : "v"(x2));
                asm("v_exp_f32 %0, %1" : "=v"(e3) : "v"(x3));
                asm("v_exp_f32 %0, %1" : "=v"(e4) : "v"(x4));
                asm("v_exp_f32 %0, %1" : "=v"(e5) : "v"(x5));
                asm("v_exp_f32 %0, %1" : "=v"(e6) : "v"(x6));
                asm("v_exp_f32 %0, %1" : "=v"(e7) : "v"(x7));
            }
            s0 += e0 + e4; s1 += e1 + e5; s2 += e2 + e6; s3 += e3 + e7;
            unsigned int E0, E1, O0, O1;
            asm("v_cvt_pk_bf16_f32 %0, %1, %2" : "=v"(E0) : "v"(e0), "v"(e1));
            asm("v_cvt_pk_bf16_f32 %0, %1, %2" : "=v"(E1) : "v"(e2), "v"(e3));
            asm("v_cvt_pk_bf16_f32 %0, %1, %2" : "=v"(O0) : "v"(e4), "v"(e5));
            asm("v_cvt_pk_bf16_f32 %0, %1, %2" : "=v"(O1) : "v"(e6), "v"(e7));
            unsigned int m0_ = hi ? O0 : E0, m1_ = hi ? O1 : E1;
            unsigned int s0_ = hi ? E0 : O0, s1_ = hi ? E1 : O1;
            unsigned int g0 = __shfl_xor(s0_, 32), g1 = __shfl_xor(s1_, 32);
            unsigned int X00 = hi ? g0 : m0_, X01 = hi ? g1 : m1_;
            unsigned int X10 = hi ? m0_ : g0, X11 = hi ? m1_ : g1;
            unsigned int k0 = odd ? X10 : X00, k1 = odd ? X11 : X01;
            unsigned int t0 = odd ? X00 : X10, t1 = odd ? X01 : X11;
            unsigned int r0 = __shfl_xor(t0, 16), r1 = __shfl_xor(t1, 16);
            union { unsigned int u[4]; bf16x8 v; } pu;
            pu.u[0] = odd ? r0 : k0; pu.u[1] = odd ? r1 : k1;
            pu.u[2] = odd ? k0 : r0; pu.u[3] = odd ? k1 : r1;
            union { unsigned int u[4]; bf16x8 v; } bu;
            {
                int c = 255 + 32 * m + 8 * l4 - (q0 + qrow);
                const unsigned short* arr = (c & 1) ? brO : brE;
                int cb = c & ~1;
                bu.u[0] = *(const unsigned int*)&arr[cb];
                bu.u[1] = *(const unsigned int*)&arr[cb + 2];
                bu.u[2] = *(const unsigned int*)&arr[cb + 4];
                bu.u[3] = *(const unsigned int*)&arr[cb + 6];
            }
            int vc = (m * 4 + l4) ^ (l15 & 7);
            bf16x8 v0 = *(const bf16x8*)&vt_l[l15 * 256 + vc * 8];
            bf16x8 v1 = *(const bf16x8*)&vt_l[(16 + l15) * 256 + vc * 8];
            o0 = MFMA16(pu.v, v0, o0);
            o1 = MFMA16(pu.v, v1, o1);
            c20 = MFMA16(bu.v, v0, c20);
            c21 = MFMA16(bu.v, v1, c21);
        }

        float sum = (s0 + s1) + (s2 + s3);
        sum += __shfl_xor(sum, 16);
        sum += __shfl_xor(sum, 32);
        float inv = 1.0f / sum;

#pragma unroll
        for (int r = 0; r < 4; ++r) {
            float ivr = __shfl(inv, 4 * l4 + r);
            int s = q0 + 16 * wave + l4 * 4 + r;
            float* po = out + ((size_t)(b * 256 + s)) * 512 + h * 32;
            __builtin_nontemporal_store(o0[r] * ivr + c20[r], po + l15);
            __builtin_nontemporal_store(o1[r] * ivr + c21[r], po + 16 + l15);
        }
        if (qb < 3) qcur = qnext;
    }
}

// ---------------- launch ----------------
extern "C" void kernel_launch(void* const* d_in, const int* in_sizes, int n_in,
                              void* d_out, int out_size, void* d_ws, size_t ws_size,
                              hipStream_t stream) {
    const float* hs = (const float*)d_in[0];
    const float* Wq = (const float*)d_in[1];
    const float* bq = (const float*)d_in[2];
    const float* Wk = (const float*)d_in[3];
    const float* bk = (const float*)d_in[4];
    const float* Wv = (const float*)d_in[5];
    const float* bv = (const float*)d_in[6];
    const float* bt = (const float*)d_in[7];
    float* out = (float*)d_out;

    char* ws = (char*)d_ws;
    unsigned short* hsb = (unsigned short*)ws;                 // 16,777,216 B (row-major bf16)
    unsigned short* wt = (unsigned short*)(ws + 16777216);     //  1,572,864 B ([n][k] row-major)
    unsigned short* Qo = (unsigned short*)(ws + 18350080);     // 16,777,216 B
    unsigned short* Ko = (unsigned short*)(ws + 35127296);     // 16,777,216 B
    unsigned short* Vo = (unsigned short*)(ws + 51904512);     // 16,777,216 B ([b][h][dh][s])
    float* cs2 = (float*)(ws + 68681728);                      //     32,768 B

    hipLaunchKernelGGL(k_cvt, dim3(8192), dim3(256), 0, stream, (const float4*)hs, hsb);
    hipLaunchKernelGGL(k_wt, dim3(8, 8, 3), dim3(256), 0, stream, Wq, Wk, Wv, wt);
    hipLaunchKernelGGL(k_sc, dim3(1), dim3(256), 0, stream, cs2);
    hipLaunchKernelGGL(k_gemm, dim3(1536), dim3(256), 0, stream,
                       hsb, wt, bq, bk, bv, cs2, Qo, Ko, Vo);
    hipLaunchKernelGGL(k_attn, dim3(1024), dim3(256), 0, stream,
                       Qo, Ko, Vo, bt, out);
}